// Round 14
// baseline (219.741 us; speedup 1.0000x reference)
//
#include <hip/hip_runtime.h>
#include <math.h>

#define B 8
#define S 2048
#define D_MODEL 512
#define NK 256      // n_kernels (conv out channels / attention feature dim)
#define KSZ 9
#define NC 4096     // n_classes
#define PADW 4
#define SSPLIT 4    // attention s-dimension split
#define CM 64       // conv s-rows per block (r8/r10-proven; CM=32 and twin-split both regressed)
#define CW (CM + 8) // staged window rows (72)
#define NSTG (KSZ * 16)                // 144 K-stages: stg = t*16 + h (h = 32-d chunk)
#define NTILES ((S / SSPLIT) / 32)     // 16 x-tiles per attn block

typedef __attribute__((ext_vector_type(8))) short bf16x8;
typedef __attribute__((ext_vector_type(4))) float f32x4;
typedef __attribute__((ext_vector_type(16))) float f32x16;

static __device__ __forceinline__ unsigned short f2bf(float f) {
    unsigned int u = __float_as_uint(f);
    unsigned int r = (u + 0x7fffu + ((u >> 16) & 1u)) >> 16;
    return (unsigned short)r;
}

#define GLOAD_LDS16(g, l) __builtin_amdgcn_global_load_lds( \
    (const __attribute__((address_space(1))) void*)(g),     \
    (__attribute__((address_space(3))) void*)(l), 16, 0, 0)

// ---- fused prep ----------------------------------------------------------
// r13: W-branch inverted to READ-coalesced. Old version read w at stride
// 36B (consecutive dd -> (k*512+d)*9+t): every lane pulled a 64B line for
// 4B = ~75MB of line traffic for a 4.7MB tensor, fully latency/BW-wasteful.
// Now each thread reads ONE float4 of w linearly (a float4 never crosses a
// k boundary: 4608%4==0) and scatter-writes 4 bf16 into wtb — the scatter
// targets a 2.36MB L2/L3-resident buffer where it is absorbed.
// U/F branches unchanged (already float4-coalesced).
#define PREP_W (KSZ * NK * D_MODEL)
#define PREP_W4 (PREP_W / 4)
#define PREP_UF (NC * NK)
#define PREP_N (PREP_W4 + (2 * PREP_UF) / 4)
__global__ __launch_bounds__(256) void prep_all(
    const float* __restrict__ w, unsigned short* __restrict__ wtb,
    const float* __restrict__ U, unsigned short* __restrict__ Ub,
    const float* __restrict__ F, unsigned short* __restrict__ Fb)
{
    const float LOG2E = 1.44269504088896340736f;
    int idx = blockIdx.x * 256 + threadIdx.x;
    if (idx < PREP_W4) {
        float4 v = ((const float4*)w)[idx];     // coalesced
        int flat = idx * 4;
        int k = flat / (D_MODEL * KSZ);         // magic-mul
        int r = flat - k * (D_MODEL * KSZ);
        float vv[4] = {v.x, v.y, v.z, v.w};
        #pragma unroll
        for (int i = 0; i < 4; i++) {
            int ri = r + i;
            int d = ri / KSZ;
            int t = ri - d * KSZ;
            // wtb[stg][k][dd], stg = t*16 + (d>>5)
            wtb[(size_t)(t * 16 + (d >> 5)) * (NK * 32) + k * 32 + (d & 31)] = f2bf(vv[i]);
        }
        return;
    }
    idx -= PREP_W4;
    if (idx < PREP_UF / 4) {
        float4 v = ((const float4*)U)[idx];
        ushort4 o;
        o.x = f2bf(v.x * LOG2E); o.y = f2bf(v.y * LOG2E);
        o.z = f2bf(v.z * LOG2E); o.w = f2bf(v.w * LOG2E);
        ((ushort4*)Ub)[idx] = o;
        return;
    }
    idx -= PREP_UF / 4;
    if (idx < PREP_UF / 4) {
        float4 v = ((const float4*)F)[idx];
        ushort4 o;
        o.x = f2bf(v.x); o.y = f2bf(v.y);
        o.z = f2bf(v.z); o.w = f2bf(v.w);
        ((ushort4*)Fb)[idx] = o;
    }
}

// ---- embed-gather + MFMA conv1d + bias + tanh -> xf bf16 [b][s][k] --------
// r10-exact (r8-proven optimum): window staged once, ONE barrier, depth-3
// static software pipeline, 8 waves M64xN32, stage-contiguous weight stream.
// Variants tested and regressed: CM=32 (r11, broke depth-3 latency cover,
// 87us), channel-split twins (r12, neutral-worse + polluted attn's L2).
__global__ __launch_bounds__(512, 2) void conv_mfma(
    const int* __restrict__ text, const float* __restrict__ emb,
    const unsigned short* __restrict__ wtb, const float* __restrict__ bias,
    unsigned short* __restrict__ xf)
{
    __shared__ unsigned short xs[CW * D_MODEL];   // 73,728 B
    const int b  = blockIdx.x >> 5;               // S/CM = 32 s-blocks
    const int s0 = (blockIdx.x & 31) * CM;
    const int tid = threadIdx.x;

    for (int u = tid; u < CW * 64; u += 512) {
        int row = u >> 6, c = u & 63;             // c = logical 16B chunk
        int gs = s0 + row - PADW;
        float4 v0 = make_float4(0.f, 0.f, 0.f, 0.f), v1 = v0;
        if (gs >= 0 && gs < S) {
            int tok = text[b * S + gs];
            const float4* e4 = (const float4*)(emb + (size_t)tok * D_MODEL + c * 8);
            v0 = e4[0]; v1 = e4[1];
        }
        union { bf16x8 v; unsigned short us[8]; } pk;
        pk.us[0] = f2bf(v0.x); pk.us[1] = f2bf(v0.y);
        pk.us[2] = f2bf(v0.z); pk.us[3] = f2bf(v0.w);
        pk.us[4] = f2bf(v1.x); pk.us[5] = f2bf(v1.y);
        pk.us[6] = f2bf(v1.z); pk.us[7] = f2bf(v1.w);
        int phys = c ^ (row & 7);
        *(bf16x8*)(xs + row * D_MODEL + phys * 8) = pk.v;
    }
    __syncthreads();                              // the ONLY barrier

    const int wv   = tid >> 6;                    // 0..7
    const int lane = tid & 63;
    const int cl   = lane & 15;
    const int quad = lane >> 4;
    const int n0   = wv * 32;                     // 8 waves cover 256 channels

    bf16x8 A0[4], A1[4], A2[4], B0[2], B1[2], B2[2];
    f32x4 acc[4][2] = {};

    #define LDB(BB, stg)                                                      \
        {                                                                     \
            const unsigned short* wp = wtb + (size_t)(stg) * (NK * 32)        \
                                       + (n0 + cl) * 32 + quad * 8;           \
            BB[0] = *(const bf16x8*)(wp);                                     \
            BB[1] = *(const bf16x8*)(wp + 16 * 32);                           \
        }
    #define LDA(AA, stg)                                                      \
        {                                                                     \
            int t_ = (stg) >> 4, h_ = (stg) & 15;                             \
            _Pragma("unroll")                                                 \
            for (int ms = 0; ms < 4; ms++) {                                  \
                int row = cl + ms * 16 + t_;                                  \
                int ph  = (h_ * 4 + quad) ^ (row & 7);                        \
                AA[ms] = *(const bf16x8*)(xs + row * D_MODEL + ph * 8);       \
            }                                                                 \
        }
    #define FENCE asm volatile("" ::: "memory");
    #define DOMFMA(AA, BB)                                                    \
        _Pragma("unroll")                                                     \
        for (int ms = 0; ms < 4; ms++) {                                      \
            acc[ms][0] = __builtin_amdgcn_mfma_f32_16x16x32_bf16(AA[ms], BB[0], acc[ms][0], 0, 0, 0); \
            acc[ms][1] = __builtin_amdgcn_mfma_f32_16x16x32_bf16(AA[ms], BB[1], acc[ms][1], 0, 0, 0); \
        }

    LDB(B0, 0) LDA(A0, 0) LDB(B1, 1) LDA(A1, 1) LDB(B2, 2) LDA(A2, 2) FENCE

    for (int ss = 0; ss < NSTG; ss += 3) {        // 48 iters
        DOMFMA(A0, B0)
        if (ss + 3 < NSTG) { LDB(B0, ss + 3) LDA(A0, ss + 3) FENCE }
        DOMFMA(A1, B1)
        if (ss + 4 < NSTG) { LDB(B1, ss + 4) LDA(A1, ss + 4) FENCE }
        DOMFMA(A2, B2)
        if (ss + 5 < NSTG) { LDB(B2, ss + 5) LDA(A2, ss + 5) FENCE }
    }

    #pragma unroll
    for (int ns = 0; ns < 2; ns++) {
        const int k = n0 + ns * 16 + cl;
        const float bk = bias[k];
        #pragma unroll
        for (int ms = 0; ms < 4; ms++) {
            #pragma unroll
            for (int r = 0; r < 4; r++) {
                int s = s0 + ms * 16 + quad * 4 + r;
                float v = acc[ms][ns][r] + bk;
                float e = __expf(2.f * v);
                float th = 1.f - 2.f / (e + 1.f); // tanh(v)
                xf[((size_t)b * S + s) * NK + k] = f2bf(th);
            }
        }
    }
}

// -------- MFMA attention: max-free softmax, bf16 U/F tables ----------------
// r10 config (32x32x16): bank conflicts halved vs 16x16, VALU 17%, ~68us =
// 40% of dense peak — the documented plateau for non-8-phase structures.
// attn considered locally converged; kept as-is.
#define WAITVM4 asm volatile("s_waitcnt vmcnt(4)" ::: "memory")
#define WAITVM0 asm volatile("s_waitcnt vmcnt(0)" ::: "memory")
__global__ __launch_bounds__(256, 2) void attn_mfma(
    const unsigned short* __restrict__ xf, const unsigned short* __restrict__ Ub,
    const unsigned short* __restrict__ Fb, float* __restrict__ pl,
    float* __restrict__ pg)
{
    __shared__ unsigned short xsa[3 * 32 * NK];   // 3 x 16 KB
    const int b    = blockIdx.z;
    const int sp   = blockIdx.y;
    const int tid  = threadIdx.x;
    const int wv   = tid >> 6;
    const int lane = tid & 63;
    const int row  = lane & 31;                   // A s-row / B class row
    const int bh   = lane >> 5;                   // k-half selector
    const int c0   = blockIdx.x * 128 + wv * 32;  // 32 classes per wave
    const int wvu  = __builtin_amdgcn_readfirstlane(wv);

    // B tables: class = lane&31, k = bh*8 + kk*16 .. +8  (16 slices)
    bf16x8 uf[16], ff[16];
    {
        const unsigned short* up = Ub + (size_t)(c0 + row) * NK + bh * 8;
        const unsigned short* fp = Fb + (size_t)(c0 + row) * NK + bh * 8;
        #pragma unroll
        for (int kk = 0; kk < 16; kk++) {
            uf[kk] = *(const bf16x8*)(up + kk * 16);
            ff[kk] = *(const bf16x8*)(fp + kk * 16);
        }
    }

    const int sbeg = sp * (S / SSPLIT);
    const unsigned short* xb = xf + ((size_t)b * S + sbeg) * NK;

    // hoisted staging pointers (loop-invariant; only t*32*NK varies)
    const unsigned short* ssrc[4];
    unsigned short* sdst[4];
    #pragma unroll
    for (int j = 0; j < 4; j++) {
        int C = j * 256 + tid;
        int r = C >> 5, p = C & 31;
        int jl = p ^ (r & 7);
        ssrc[j] = xb + (size_t)r * NK + jl * 8;
        sdst[j] = xsa + j * 2048 + wvu * 512;
    }

    #define STAGE(bb, t)                                                      \
        {                                                                     \
            _Pragma("unroll")                                                 \
            for (int j = 0; j < 4; j++)                                       \
                GLOAD_LDS16(ssrc[j] + (t) * (32 * NK), sdst[j] + (bb) * 8192);\
        }

    STAGE(0, 0)
    STAGE(1, 1)

    const int sw = row & 7;
    float l = 0.f, G = 0.f;

    #pragma unroll
    for (int t = 0; t < NTILES; t++) {            // fully unrolled: buf static
        if (t + 1 < NTILES) { WAITVM4; } else { WAITVM0; }
        __builtin_amdgcn_s_barrier();
        if (t + 2 < NTILES) STAGE((t + 2) % 3, t + 2)

        const unsigned short* bs = xsa + (t % 3) * 8192 + row * NK;
        f32x16 sa = {}, ga = {};
        #pragma unroll
        for (int kk = 0; kk < 16; kk++) {
            int ch = 2 * kk + bh;                 // logical 16B chunk
            int ph = (ch & ~7) | ((ch & 7) ^ sw); // swizzled (low 3 bits)
            bf16x8 a = *(const bf16x8*)(bs + ph * 8);
            sa = __builtin_amdgcn_mfma_f32_32x32x16_bf16(a, uf[kk], sa, 0, 0, 0);
            ga = __builtin_amdgcn_mfma_f32_32x32x16_bf16(a, ff[kk], ga, 0, 0, 0);
        }

        // max-free softmax accumulation (rows fully in-register)
        #pragma unroll
        for (int r = 0; r < 16; r++) {
            float e = __builtin_amdgcn_exp2f(sa[r]);
            l += e;
            G += e * ga[r];
        }
    }

    // rows split across lane-halves only: one xor-32 finishes the s-reduce
    l += __shfl_xor(l, 32);
    G += __shfl_xor(G, 32);
    if (lane < 32) {
        size_t idx = ((size_t)b * SSPLIT + sp) * NC + c0 + lane;
        pl[idx] = l; pg[idx] = G;
    }
}

// -------- combine S-split partials + bias -> y [b][c] ----------------------
__global__ __launch_bounds__(256) void combine_kernel(
    const float* __restrict__ pl, const float* __restrict__ pg,
    const float* __restrict__ fb, float* __restrict__ out)
{
    int idx = blockIdx.x * 256 + threadIdx.x;     // over B*NC
    if (idx >= B * NC) return;
    int b = idx / NC, c = idx % NC;
    float l = 0.f, g = 0.f;
    #pragma unroll
    for (int sp = 0; sp < SSPLIT; sp++) {
        size_t i = ((size_t)b * SSPLIT + sp) * NC + c;
        l += pl[i];
        g += pg[i];
    }
    out[idx] = g / l + fb[c];
}

extern "C" void kernel_launch(void* const* d_in, const int* in_sizes, int n_in,
                              void* d_out, int out_size, void* d_ws, size_t ws_size,
                              hipStream_t stream) {
    const int*   text   = (const int*)  d_in[0];
    const float* emb    = (const float*)d_in[1];
    const float* conv_w = (const float*)d_in[2];
    const float* conv_b = (const float*)d_in[3];
    const float* U_w    = (const float*)d_in[4];
    const float* F_w    = (const float*)d_in[5];
    const float* f_b    = (const float*)d_in[6];
    float* out = (float*)d_out;

    char* ws = (char*)d_ws;
    unsigned short* xf  = (unsigned short*)ws; ws += (size_t)B * S * NK * 2;
    unsigned short* wtb = (unsigned short*)ws; ws += (size_t)KSZ * NK * D_MODEL * 2;
    unsigned short* Ub  = (unsigned short*)ws; ws += (size_t)NC * NK * 2;
    unsigned short* Fb  = (unsigned short*)ws; ws += (size_t)NC * NK * 2;
    float* pl = (float*)ws; ws += (size_t)SSPLIT * B * NC * 4;
    float* pg = (float*)ws; ws += (size_t)SSPLIT * B * NC * 4;

    prep_all<<<dim3((PREP_N + 255) / 256), 256, 0, stream>>>(conv_w, wtb, U_w, Ub, F_w, Fb);
    conv_mfma<<<dim3(B * S / CM), 512, 0, stream>>>(text, emb, wtb, conv_b, xf);
    attn_mfma<<<dim3(NC / 128, SSPLIT, B), 256, 0, stream>>>(xf, Ub, Fb, pl, pg);
    combine_kernel<<<dim3((B * NC + 255) / 256), 256, 0, stream>>>(pl, pg, f_b, out);
}

// Round 15
// 219.099 us; speedup vs baseline: 1.0029x; 1.0029x over previous
//
#include <hip/hip_runtime.h>
#include <math.h>

#define B 8
#define S 2048
#define D_MODEL 512
#define NK 256      // n_kernels (conv out channels / attention feature dim)
#define KSZ 9
#define NC 4096     // n_classes
#define PADW 4
#define SSPLIT 4    // attention s-dimension split
#define CM 64       // conv s-rows per block (r8/r10-proven; CM=32 and twin-split both regressed)
#define CW (CM + 8) // staged window rows (72)
#define NSTG (KSZ * 16)                // 144 K-stages: stg = t*16 + h (h = 32-d chunk)
#define NTILES ((S / SSPLIT) / 32)     // 16 x-tiles per attn block

typedef __attribute__((ext_vector_type(8))) short bf16x8;
typedef __attribute__((ext_vector_type(4))) float f32x4;
typedef __attribute__((ext_vector_type(16))) float f32x16;

static __device__ __forceinline__ unsigned short f2bf(float f) {
    unsigned int u = __float_as_uint(f);
    unsigned int r = (u + 0x7fffu + ((u >> 16) & 1u)) >> 16;
    return (unsigned short)r;
}

#define GLOAD_LDS16(g, l) __builtin_amdgcn_global_load_lds( \
    (const __attribute__((address_space(1))) void*)(g),     \
    (__attribute__((address_space(3))) void*)(l), 16, 0, 0)

// ---- fused prep: conv_w -> wtb [stg][k][d32] bf16 (stage-contig 16KB);
// ---- U (pre-scaled by log2e) / F fp32 -> bf16, 4 elems/thread vectorized --
// (r10 version restored: r13/r14's read-coalesced/write-scattered variant
// was neutral-to-worse — the 2B scatter writes cost >= the strided reads.)
#define PREP_W (KSZ * NK * D_MODEL)
#define PREP_UF (NC * NK)
#define PREP_N (PREP_W + (2 * PREP_UF) / 4)
__global__ __launch_bounds__(256) void prep_all(
    const float* __restrict__ w, unsigned short* __restrict__ wtb,
    const float* __restrict__ U, unsigned short* __restrict__ Ub,
    const float* __restrict__ F, unsigned short* __restrict__ Fb)
{
    const float LOG2E = 1.44269504088896340736f;
    int idx = blockIdx.x * 256 + threadIdx.x;
    if (idx < PREP_W) {
        int dd  = idx & 31;
        int k   = (idx >> 5) & (NK - 1);
        int stg = idx >> 13;              // / (32*NK)
        int t = stg >> 4, h = stg & 15;
        wtb[idx] = f2bf(w[((size_t)k * D_MODEL + h * 32 + dd) * KSZ + t]);
        return;
    }
    idx -= PREP_W;
    if (idx < PREP_UF / 4) {
        float4 v = ((const float4*)U)[idx];
        ushort4 o;
        o.x = f2bf(v.x * LOG2E); o.y = f2bf(v.y * LOG2E);
        o.z = f2bf(v.z * LOG2E); o.w = f2bf(v.w * LOG2E);
        ((ushort4*)Ub)[idx] = o;
        return;
    }
    idx -= PREP_UF / 4;
    if (idx < PREP_UF / 4) {
        float4 v = ((const float4*)F)[idx];
        ushort4 o;
        o.x = f2bf(v.x); o.y = f2bf(v.y);
        o.z = f2bf(v.z); o.w = f2bf(v.w);
        ((ushort4*)Fb)[idx] = o;
    }
}

// ---- embed-gather + MFMA conv1d + bias + tanh -> xf bf16 [b][s][k] --------
// r15: asymmetric pipeline depth — B (global wtb, L2-resident) deepened to
// 6 buffers, A (LDS) stays at proven depth 3. Theory: old code issued
// LDB(ss+3) after DOMFMA(ss) => ~2-stage (~130cy) cover < warm-L2 latency
// (~200-250cy) — every stage ate a residual B-wait stall (conv ~62us vs
// 18.6us MFMA floor, MfmaUtil ~28%). Now LDB(ss+6) => ~5-stage (~325cy)
// cover. VGPR: 48(B)+48(A)+32(acc)+addr ~ 150 <= 256 cap at lb(512,2)
// (2 waves/SIMD => 256 VGPR each — r14 post-mortem corrected this budget).
// Unroll 6 (144%6==0); prologue loads B0..B5/A0..A2; guards verified at
// ss=138 tail. CM=32 (r11) and twin-split (r12) remain regressions.
__global__ __launch_bounds__(512, 2) void conv_mfma(
    const int* __restrict__ text, const float* __restrict__ emb,
    const unsigned short* __restrict__ wtb, const float* __restrict__ bias,
    unsigned short* __restrict__ xf)
{
    __shared__ unsigned short xs[CW * D_MODEL];   // 73,728 B
    const int b  = blockIdx.x >> 5;               // S/CM = 32 s-blocks
    const int s0 = (blockIdx.x & 31) * CM;
    const int tid = threadIdx.x;

    for (int u = tid; u < CW * 64; u += 512) {
        int row = u >> 6, c = u & 63;             // c = logical 16B chunk
        int gs = s0 + row - PADW;
        float4 v0 = make_float4(0.f, 0.f, 0.f, 0.f), v1 = v0;
        if (gs >= 0 && gs < S) {
            int tok = text[b * S + gs];
            const float4* e4 = (const float4*)(emb + (size_t)tok * D_MODEL + c * 8);
            v0 = e4[0]; v1 = e4[1];
        }
        union { bf16x8 v; unsigned short us[8]; } pk;
        pk.us[0] = f2bf(v0.x); pk.us[1] = f2bf(v0.y);
        pk.us[2] = f2bf(v0.z); pk.us[3] = f2bf(v0.w);
        pk.us[4] = f2bf(v1.x); pk.us[5] = f2bf(v1.y);
        pk.us[6] = f2bf(v1.z); pk.us[7] = f2bf(v1.w);
        int phys = c ^ (row & 7);
        *(bf16x8*)(xs + row * D_MODEL + phys * 8) = pk.v;
    }
    __syncthreads();                              // the ONLY barrier

    const int wv   = tid >> 6;                    // 0..7
    const int lane = tid & 63;
    const int cl   = lane & 15;
    const int quad = lane >> 4;
    const int n0   = wv * 32;                     // 8 waves cover 256 channels

    bf16x8 A0[4], A1[4], A2[4];
    bf16x8 B0[2], B1[2], B2[2], B3[2], B4[2], B5[2];
    f32x4 acc[4][2] = {};

    #define LDB(BB, stg)                                                      \
        {                                                                     \
            const unsigned short* wp = wtb + (size_t)(stg) * (NK * 32)        \
                                       + (n0 + cl) * 32 + quad * 8;           \
            BB[0] = *(const bf16x8*)(wp);                                     \
            BB[1] = *(const bf16x8*)(wp + 16 * 32);                           \
        }
    #define LDA(AA, stg)                                                      \
        {                                                                     \
            int t_ = (stg) >> 4, h_ = (stg) & 15;                             \
            _Pragma("unroll")                                                 \
            for (int ms = 0; ms < 4; ms++) {                                  \
                int row = cl + ms * 16 + t_;                                  \
                int ph  = (h_ * 4 + quad) ^ (row & 7);                        \
                AA[ms] = *(const bf16x8*)(xs + row * D_MODEL + ph * 8);       \
            }                                                                 \
        }
    #define FENCE asm volatile("" ::: "memory");
    #define DOMFMA(AA, BB)                                                    \
        _Pragma("unroll")                                                     \
        for (int ms = 0; ms < 4; ms++) {                                      \
            acc[ms][0] = __builtin_amdgcn_mfma_f32_16x16x32_bf16(AA[ms], BB[0], acc[ms][0], 0, 0, 0); \
            acc[ms][1] = __builtin_amdgcn_mfma_f32_16x16x32_bf16(AA[ms], BB[1], acc[ms][1], 0, 0, 0); \
        }

    LDB(B0, 0) LDB(B1, 1) LDB(B2, 2) LDB(B3, 3) LDB(B4, 4) LDB(B5, 5)
    LDA(A0, 0) LDA(A1, 1) LDA(A2, 2) FENCE

    for (int ss = 0; ss < NSTG; ss += 6) {        // 24 iters, 6 stages each
        DOMFMA(A0, B0)
        if (ss + 6 < NSTG) LDB(B0, ss + 6)
        if (ss + 3 < NSTG) LDA(A0, ss + 3)
        FENCE
        DOMFMA(A1, B1)
        if (ss + 7 < NSTG) LDB(B1, ss + 7)
        if (ss + 4 < NSTG) LDA(A1, ss + 4)
        FENCE
        DOMFMA(A2, B2)
        if (ss + 8 < NSTG) LDB(B2, ss + 8)
        if (ss + 5 < NSTG) LDA(A2, ss + 5)
        FENCE
        DOMFMA(A0, B3)
        if (ss + 9 < NSTG) LDB(B3, ss + 9)
        if (ss + 6 < NSTG) LDA(A0, ss + 6)
        FENCE
        DOMFMA(A1, B4)
        if (ss + 10 < NSTG) LDB(B4, ss + 10)
        if (ss + 7 < NSTG) LDA(A1, ss + 7)
        FENCE
        DOMFMA(A2, B5)
        if (ss + 11 < NSTG) LDB(B5, ss + 11)
        if (ss + 8 < NSTG) LDA(A2, ss + 8)
        FENCE
    }

    #pragma unroll
    for (int ns = 0; ns < 2; ns++) {
        const int k = n0 + ns * 16 + cl;
        const float bk = bias[k];
        #pragma unroll
        for (int ms = 0; ms < 4; ms++) {
            #pragma unroll
            for (int r = 0; r < 4; r++) {
                int s = s0 + ms * 16 + quad * 4 + r;
                float v = acc[ms][ns][r] + bk;
                float e = __expf(2.f * v);
                float th = 1.f - 2.f / (e + 1.f); // tanh(v)
                xf[((size_t)b * S + s) * NK + k] = f2bf(th);
            }
        }
    }
}

// -------- MFMA attention: max-free softmax, bf16 U/F tables ----------------
// r10 config (32x32x16): bank conflicts halved vs 16x16, VALU 17%, ~68us =
// 40% of dense peak — the documented plateau for non-8-phase structures.
// attn considered locally converged; kept as-is.
#define WAITVM4 asm volatile("s_waitcnt vmcnt(4)" ::: "memory")
#define WAITVM0 asm volatile("s_waitcnt vmcnt(0)" ::: "memory")
__global__ __launch_bounds__(256, 2) void attn_mfma(
    const unsigned short* __restrict__ xf, const unsigned short* __restrict__ Ub,
    const unsigned short* __restrict__ Fb, float* __restrict__ pl,
    float* __restrict__ pg)
{
    __shared__ unsigned short xsa[3 * 32 * NK];   // 3 x 16 KB
    const int b    = blockIdx.z;
    const int sp   = blockIdx.y;
    const int tid  = threadIdx.x;
    const int wv   = tid >> 6;
    const int lane = tid & 63;
    const int row  = lane & 31;                   // A s-row / B class row
    const int bh   = lane >> 5;                   // k-half selector
    const int c0   = blockIdx.x * 128 + wv * 32;  // 32 classes per wave
    const int wvu  = __builtin_amdgcn_readfirstlane(wv);

    // B tables: class = lane&31, k = bh*8 + kk*16 .. +8  (16 slices)
    bf16x8 uf[16], ff[16];
    {
        const unsigned short* up = Ub + (size_t)(c0 + row) * NK + bh * 8;
        const unsigned short* fp = Fb + (size_t)(c0 + row) * NK + bh * 8;
        #pragma unroll
        for (int kk = 0; kk < 16; kk++) {
            uf[kk] = *(const bf16x8*)(up + kk * 16);
            ff[kk] = *(const bf16x8*)(fp + kk * 16);
        }
    }

    const int sbeg = sp * (S / SSPLIT);
    const unsigned short* xb = xf + ((size_t)b * S + sbeg) * NK;

    // hoisted staging pointers (loop-invariant; only t*32*NK varies)
    const unsigned short* ssrc[4];
    unsigned short* sdst[4];
    #pragma unroll
    for (int j = 0; j < 4; j++) {
        int C = j * 256 + tid;
        int r = C >> 5, p = C & 31;
        int jl = p ^ (r & 7);
        ssrc[j] = xb + (size_t)r * NK + jl * 8;
        sdst[j] = xsa + j * 2048 + wvu * 512;
    }

    #define STAGE(bb, t)                                                      \
        {                                                                     \
            _Pragma("unroll")                                                 \
            for (int j = 0; j < 4; j++)                                       \
                GLOAD_LDS16(ssrc[j] + (t) * (32 * NK), sdst[j] + (bb) * 8192);\
        }

    STAGE(0, 0)
    STAGE(1, 1)

    const int sw = row & 7;
    float l = 0.f, G = 0.f;

    #pragma unroll
    for (int t = 0; t < NTILES; t++) {            // fully unrolled: buf static
        if (t + 1 < NTILES) { WAITVM4; } else { WAITVM0; }
        __builtin_amdgcn_s_barrier();
        if (t + 2 < NTILES) STAGE((t + 2) % 3, t + 2)

        const unsigned short* bs = xsa + (t % 3) * 8192 + row * NK;
        f32x16 sa = {}, ga = {};
        #pragma unroll
        for (int kk = 0; kk < 16; kk++) {
            int ch = 2 * kk + bh;                 // logical 16B chunk
            int ph = (ch & ~7) | ((ch & 7) ^ sw); // swizzled (low 3 bits)
            bf16x8 a = *(const bf16x8*)(bs + ph * 8);
            sa = __builtin_amdgcn_mfma_f32_32x32x16_bf16(a, uf[kk], sa, 0, 0, 0);
            ga = __builtin_amdgcn_mfma_f32_32x32x16_bf16(a, ff[kk], ga, 0, 0, 0);
        }

        // max-free softmax accumulation (rows fully in-register)
        #pragma unroll
        for (int r = 0; r < 16; r++) {
            float e = __builtin_amdgcn_exp2f(sa[r]);
            l += e;
            G += e * ga[r];
        }
    }

    // rows split across lane-halves only: one xor-32 finishes the s-reduce
    l += __shfl_xor(l, 32);
    G += __shfl_xor(G, 32);
    if (lane < 32) {
        size_t idx = ((size_t)b * SSPLIT + sp) * NC + c0 + lane;
        pl[idx] = l; pg[idx] = G;
    }
}

// -------- combine S-split partials + bias -> y [b][c] ----------------------
__global__ __launch_bounds__(256) void combine_kernel(
    const float* __restrict__ pl, const float* __restrict__ pg,
    const float* __restrict__ fb, float* __restrict__ out)
{
    int idx = blockIdx.x * 256 + threadIdx.x;     // over B*NC
    if (idx >= B * NC) return;
    int b = idx / NC, c = idx % NC;
    float l = 0.f, g = 0.f;
    #pragma unroll
    for (int sp = 0; sp < SSPLIT; sp++) {
        size_t i = ((size_t)b * SSPLIT + sp) * NC + c;
        l += pl[i];
        g += pg[i];
    }
    out[idx] = g / l + fb[c];
}

extern "C" void kernel_launch(void* const* d_in, const int* in_sizes, int n_in,
                              void* d_out, int out_size, void* d_ws, size_t ws_size,
                              hipStream_t stream) {
    const int*   text   = (const int*)  d_in[0];
    const float* emb    = (const float*)d_in[1];
    const float* conv_w = (const float*)d_in[2];
    const float* conv_b = (const float*)d_in[3];
    const float* U_w    = (const float*)d_in[4];
    const float* F_w    = (const float*)d_in[5];
    const float* f_b    = (const float*)d_in[6];
    float* out = (float*)d_out;

    char* ws = (char*)d_ws;
    unsigned short* xf  = (unsigned short*)ws; ws += (size_t)B * S * NK * 2;
    unsigned short* wtb = (unsigned short*)ws; ws += (size_t)KSZ * NK * D_MODEL * 2;
    unsigned short* Ub  = (unsigned short*)ws; ws += (size_t)NC * NK * 2;
    unsigned short* Fb  = (unsigned short*)ws; ws += (size_t)NC * NK * 2;
    float* pl = (float*)ws; ws += (size_t)SSPLIT * B * NC * 4;
    float* pg = (float*)ws; ws += (size_t)SSPLIT * B * NC * 4;

    prep_all<<<dim3((PREP_N + 255) / 256), 256, 0, stream>>>(conv_w, wtb, U_w, Ub, F_w, Fb);
    conv_mfma<<<dim3(B * S / CM), 512, 0, stream>>>(text, emb, wtb, conv_b, xf);
    attn_mfma<<<dim3(NC / 128, SSPLIT, B), 256, 0, stream>>>(xf, Ub, Fb, pl, pg);
    combine_kernel<<<dim3((B * NC + 255) / 256), 256, 0, stream>>>(pl, pg, f_b, out);
}

// Round 16
// 214.087 us; speedup vs baseline: 1.0264x; 1.0234x over previous
//
#include <hip/hip_runtime.h>
#include <math.h>

#define B 8
#define S 2048
#define D_MODEL 512
#define NK 256      // n_kernels (conv out channels / attention feature dim)
#define KSZ 9
#define NC 4096     // n_classes
#define PADW 4
#define SSPLIT 4    // attention s-dimension split
#define CM 64       // conv s-rows per block (r8/r10-proven)
#define CW (CM + 8) // staged window rows (72)
#define NSTG (KSZ * 16)                // 144 K-stages: stg = t*16 + h (h = 32-d chunk)
#define NTILES ((S / SSPLIT) / 32)     // 16 x-tiles per attn block

typedef __attribute__((ext_vector_type(8))) short bf16x8;
typedef __attribute__((ext_vector_type(4))) float f32x4;
typedef __attribute__((ext_vector_type(16))) float f32x16;

static __device__ __forceinline__ unsigned short f2bf(float f) {
    unsigned int u = __float_as_uint(f);
    unsigned int r = (u + 0x7fffu + ((u >> 16) & 1u)) >> 16;
    return (unsigned short)r;
}

#define GLOAD_LDS16(g, l) __builtin_amdgcn_global_load_lds( \
    (const __attribute__((address_space(1))) void*)(g),     \
    (__attribute__((address_space(3))) void*)(l), 16, 0, 0)

// ---- fused prep ----------------------------------------------------------
// r16: prep_W transposed through LDS — BOTH sides coalesced. Old version:
// 1.18M stride-36B scalar reads (64B line per 4B used, latency-bound,
// est ~25-30us by subtraction: conv~60 + attn~68 + combine~4 + gaps ~= 213).
// r13's read-coalesced variant failed because it scattered 2B WRITES.
// Now: one block per k: read 4608 floats as 1152 coalesced float4 ->
// scatter bf16 into 9KB LDS tile [144 stg][32 dd] (LDS scatter cheap) ->
// barrier -> write 144 x 64B contiguous segments (4 lanes x bf16x8 each).
// U/F branches unchanged (already float4-coalesced).
#define PREP_W (KSZ * NK * D_MODEL)
#define PREP_UF (NC * NK)
#define UF_BLKS (PREP_UF / 4 / 256)   // 1024 blocks per table
__global__ __launch_bounds__(256) void prep_all(
    const float* __restrict__ w, unsigned short* __restrict__ wtb,
    const float* __restrict__ U, unsigned short* __restrict__ Ub,
    const float* __restrict__ F, unsigned short* __restrict__ Fb)
{
    const float LOG2E = 1.44269504088896340736f;
    int bid = blockIdx.x;
    if (bid < NK) {                               // ---- W transpose, 1 k/block
        __shared__ unsigned short lk[NSTG * 32];  // 9 KB: [stg][dd]
        const int k = bid;
        const int tid = threadIdx.x;
        const float* wk = w + (size_t)k * (D_MODEL * KSZ);
        for (int i = tid; i < (D_MODEL * KSZ) / 4; i += 256) {
            float4 v = ((const float4*)wk)[i];    // coalesced read
            int f = i * 4;
            float vv[4] = {v.x, v.y, v.z, v.w};
            #pragma unroll
            for (int j = 0; j < 4; j++) {
                int d = (f + j) / KSZ;            // const-div (magic mul)
                int t = (f + j) - d * KSZ;
                lk[(t * 16 + (d >> 5)) * 32 + (d & 31)] = f2bf(vv[j]);
            }
        }
        __syncthreads();
        for (int task = tid; task < NSTG * 4; task += 256) {
            int stg = task >> 2, part = task & 3;
            *(bf16x8*)(wtb + (size_t)stg * (NK * 32) + k * 32 + part * 8) =
                *(const bf16x8*)(lk + stg * 32 + part * 8);
        }
        return;
    }
    bid -= NK;
    if (bid < UF_BLKS) {                          // ---- U (pre-scaled log2e)
        int idx = bid * 256 + threadIdx.x;
        float4 v = ((const float4*)U)[idx];
        ushort4 o;
        o.x = f2bf(v.x * LOG2E); o.y = f2bf(v.y * LOG2E);
        o.z = f2bf(v.z * LOG2E); o.w = f2bf(v.w * LOG2E);
        ((ushort4*)Ub)[idx] = o;
        return;
    }
    bid -= UF_BLKS;
    {                                             // ---- F
        int idx = bid * 256 + threadIdx.x;
        float4 v = ((const float4*)F)[idx];
        ushort4 o;
        o.x = f2bf(v.x); o.y = f2bf(v.y);
        o.z = f2bf(v.z); o.w = f2bf(v.w);
        ((ushort4*)Fb)[idx] = o;
    }
}

// ---- embed-gather + MFMA conv1d + bias + tanh -> xf bf16 [b][s][k] --------
// r10-exact (r8-proven optimum): window staged once, ONE barrier, depth-3
// static software pipeline, 8 waves M64xN32, stage-contiguous weight stream.
// Regressions on file: CM=32 (r11, 87us), twin-split (r12), deep-B6 (r15).
__global__ __launch_bounds__(512, 2) void conv_mfma(
    const int* __restrict__ text, const float* __restrict__ emb,
    const unsigned short* __restrict__ wtb, const float* __restrict__ bias,
    unsigned short* __restrict__ xf)
{
    __shared__ unsigned short xs[CW * D_MODEL];   // 73,728 B
    const int b  = blockIdx.x >> 5;               // S/CM = 32 s-blocks
    const int s0 = (blockIdx.x & 31) * CM;
    const int tid = threadIdx.x;

    for (int u = tid; u < CW * 64; u += 512) {
        int row = u >> 6, c = u & 63;             // c = logical 16B chunk
        int gs = s0 + row - PADW;
        float4 v0 = make_float4(0.f, 0.f, 0.f, 0.f), v1 = v0;
        if (gs >= 0 && gs < S) {
            int tok = text[b * S + gs];
            const float4* e4 = (const float4*)(emb + (size_t)tok * D_MODEL + c * 8);
            v0 = e4[0]; v1 = e4[1];
        }
        union { bf16x8 v; unsigned short us[8]; } pk;
        pk.us[0] = f2bf(v0.x); pk.us[1] = f2bf(v0.y);
        pk.us[2] = f2bf(v0.z); pk.us[3] = f2bf(v0.w);
        pk.us[4] = f2bf(v1.x); pk.us[5] = f2bf(v1.y);
        pk.us[6] = f2bf(v1.z); pk.us[7] = f2bf(v1.w);
        int phys = c ^ (row & 7);
        *(bf16x8*)(xs + row * D_MODEL + phys * 8) = pk.v;
    }
    __syncthreads();                              // the ONLY barrier

    const int wv   = tid >> 6;                    // 0..7
    const int lane = tid & 63;
    const int cl   = lane & 15;
    const int quad = lane >> 4;
    const int n0   = wv * 32;                     // 8 waves cover 256 channels

    bf16x8 A0[4], A1[4], A2[4], B0[2], B1[2], B2[2];
    f32x4 acc[4][2] = {};

    #define LDB(BB, stg)                                                      \
        {                                                                     \
            const unsigned short* wp = wtb + (size_t)(stg) * (NK * 32)        \
                                       + (n0 + cl) * 32 + quad * 8;           \
            BB[0] = *(const bf16x8*)(wp);                                     \
            BB[1] = *(const bf16x8*)(wp + 16 * 32);                           \
        }
    #define LDA(AA, stg)                                                      \
        {                                                                     \
            int t_ = (stg) >> 4, h_ = (stg) & 15;                             \
            _Pragma("unroll")                                                 \
            for (int ms = 0; ms < 4; ms++) {                                  \
                int row = cl + ms * 16 + t_;                                  \
                int ph  = (h_ * 4 + quad) ^ (row & 7);                        \
                AA[ms] = *(const bf16x8*)(xs + row * D_MODEL + ph * 8);       \
            }                                                                 \
        }
    #define FENCE asm volatile("" ::: "memory");
    #define DOMFMA(AA, BB)                                                    \
        _Pragma("unroll")                                                     \
        for (int ms = 0; ms < 4; ms++) {                                      \
            acc[ms][0] = __builtin_amdgcn_mfma_f32_16x16x32_bf16(AA[ms], BB[0], acc[ms][0], 0, 0, 0); \
            acc[ms][1] = __builtin_amdgcn_mfma_f32_16x16x32_bf16(AA[ms], BB[1], acc[ms][1], 0, 0, 0); \
        }

    LDB(B0, 0) LDA(A0, 0) LDB(B1, 1) LDA(A1, 1) LDB(B2, 2) LDA(A2, 2) FENCE

    for (int ss = 0; ss < NSTG; ss += 3) {        // 48 iters
        DOMFMA(A0, B0)
        if (ss + 3 < NSTG) { LDB(B0, ss + 3) LDA(A0, ss + 3) FENCE }
        DOMFMA(A1, B1)
        if (ss + 4 < NSTG) { LDB(B1, ss + 4) LDA(A1, ss + 4) FENCE }
        DOMFMA(A2, B2)
        if (ss + 5 < NSTG) { LDB(B2, ss + 5) LDA(A2, ss + 5) FENCE }
    }

    #pragma unroll
    for (int ns = 0; ns < 2; ns++) {
        const int k = n0 + ns * 16 + cl;
        const float bk = bias[k];
        #pragma unroll
        for (int ms = 0; ms < 4; ms++) {
            #pragma unroll
            for (int r = 0; r < 4; r++) {
                int s = s0 + ms * 16 + quad * 4 + r;
                float v = acc[ms][ns][r] + bk;
                float e = __expf(2.f * v);
                float th = 1.f - 2.f / (e + 1.f); // tanh(v)
                xf[((size_t)b * S + s) * NK + k] = f2bf(th);
            }
        }
    }
}

// -------- MFMA attention: max-free softmax, bf16 U/F tables ----------------
// r10 config (32x32x16): bank conflicts halved vs 16x16, VALU 17%, ~68us =
// 40% of dense peak — the documented plateau for non-8-phase structures.
// attn considered locally converged; kept as-is.
#define WAITVM4 asm volatile("s_waitcnt vmcnt(4)" ::: "memory")
#define WAITVM0 asm volatile("s_waitcnt vmcnt(0)" ::: "memory")
__global__ __launch_bounds__(256, 2) void attn_mfma(
    const unsigned short* __restrict__ xf, const unsigned short* __restrict__ Ub,
    const unsigned short* __restrict__ Fb, float* __restrict__ pl,
    float* __restrict__ pg)
{
    __shared__ unsigned short xsa[3 * 32 * NK];   // 3 x 16 KB
    const int b    = blockIdx.z;
    const int sp   = blockIdx.y;
    const int tid  = threadIdx.x;
    const int wv   = tid >> 6;
    const int lane = tid & 63;
    const int row  = lane & 31;                   // A s-row / B class row
    const int bh   = lane >> 5;                   // k-half selector
    const int c0   = blockIdx.x * 128 + wv * 32;  // 32 classes per wave
    const int wvu  = __builtin_amdgcn_readfirstlane(wv);

    // B tables: class = lane&31, k = bh*8 + kk*16 .. +8  (16 slices)
    bf16x8 uf[16], ff[16];
    {
        const unsigned short* up = Ub + (size_t)(c0 + row) * NK + bh * 8;
        const unsigned short* fp = Fb + (size_t)(c0 + row) * NK + bh * 8;
        #pragma unroll
        for (int kk = 0; kk < 16; kk++) {
            uf[kk] = *(const bf16x8*)(up + kk * 16);
            ff[kk] = *(const bf16x8*)(fp + kk * 16);
        }
    }

    const int sbeg = sp * (S / SSPLIT);
    const unsigned short* xb = xf + ((size_t)b * S + sbeg) * NK;

    // hoisted staging pointers (loop-invariant; only t*32*NK varies)
    const unsigned short* ssrc[4];
    unsigned short* sdst[4];
    #pragma unroll
    for (int j = 0; j < 4; j++) {
        int C = j * 256 + tid;
        int r = C >> 5, p = C & 31;
        int jl = p ^ (r & 7);
        ssrc[j] = xb + (size_t)r * NK + jl * 8;
        sdst[j] = xsa + j * 2048 + wvu * 512;
    }

    #define STAGE(bb, t)                                                      \
        {                                                                     \
            _Pragma("unroll")                                                 \
            for (int j = 0; j < 4; j++)                                       \
                GLOAD_LDS16(ssrc[j] + (t) * (32 * NK), sdst[j] + (bb) * 8192);\
        }

    STAGE(0, 0)
    STAGE(1, 1)

    const int sw = row & 7;
    float l = 0.f, G = 0.f;

    #pragma unroll
    for (int t = 0; t < NTILES; t++) {            // fully unrolled: buf static
        if (t + 1 < NTILES) { WAITVM4; } else { WAITVM0; }
        __builtin_amdgcn_s_barrier();
        if (t + 2 < NTILES) STAGE((t + 2) % 3, t + 2)

        const unsigned short* bs = xsa + (t % 3) * 8192 + row * NK;
        f32x16 sa = {}, ga = {};
        #pragma unroll
        for (int kk = 0; kk < 16; kk++) {
            int ch = 2 * kk + bh;                 // logical 16B chunk
            int ph = (ch & ~7) | ((ch & 7) ^ sw); // swizzled (low 3 bits)
            bf16x8 a = *(const bf16x8*)(bs + ph * 8);
            sa = __builtin_amdgcn_mfma_f32_32x32x16_bf16(a, uf[kk], sa, 0, 0, 0);
            ga = __builtin_amdgcn_mfma_f32_32x32x16_bf16(a, ff[kk], ga, 0, 0, 0);
        }

        // max-free softmax accumulation (rows fully in-register)
        #pragma unroll
        for (int r = 0; r < 16; r++) {
            float e = __builtin_amdgcn_exp2f(sa[r]);
            l += e;
            G += e * ga[r];
        }
    }

    // rows split across lane-halves only: one xor-32 finishes the s-reduce
    l += __shfl_xor(l, 32);
    G += __shfl_xor(G, 32);
    if (lane < 32) {
        size_t idx = ((size_t)b * SSPLIT + sp) * NC + c0 + lane;
        pl[idx] = l; pg[idx] = G;
    }
}

// -------- combine S-split partials + bias -> y [b][c] ----------------------
__global__ __launch_bounds__(256) void combine_kernel(
    const float* __restrict__ pl, const float* __restrict__ pg,
    const float* __restrict__ fb, float* __restrict__ out)
{
    int idx = blockIdx.x * 256 + threadIdx.x;     // over B*NC
    if (idx >= B * NC) return;
    int b = idx / NC, c = idx % NC;
    float l = 0.f, g = 0.f;
    #pragma unroll
    for (int sp = 0; sp < SSPLIT; sp++) {
        size_t i = ((size_t)b * SSPLIT + sp) * NC + c;
        l += pl[i];
        g += pg[i];
    }
    out[idx] = g / l + fb[c];
}

extern "C" void kernel_launch(void* const* d_in, const int* in_sizes, int n_in,
                              void* d_out, int out_size, void* d_ws, size_t ws_size,
                              hipStream_t stream) {
    const int*   text   = (const int*)  d_in[0];
    const float* emb    = (const float*)d_in[1];
    const float* conv_w = (const float*)d_in[2];
    const float* conv_b = (const float*)d_in[3];
    const float* U_w    = (const float*)d_in[4];
    const float* F_w    = (const float*)d_in[5];
    const float* f_b    = (const float*)d_in[6];
    float* out = (float*)d_out;

    char* ws = (char*)d_ws;
    unsigned short* xf  = (unsigned short*)ws; ws += (size_t)B * S * NK * 2;
    unsigned short* wtb = (unsigned short*)ws; ws += (size_t)KSZ * NK * D_MODEL * 2;
    unsigned short* Ub  = (unsigned short*)ws; ws += (size_t)NC * NK * 2;
    unsigned short* Fb  = (unsigned short*)ws; ws += (size_t)NC * NK * 2;
    float* pl = (float*)ws; ws += (size_t)SSPLIT * B * NC * 4;
    float* pg = (float*)ws; ws += (size_t)SSPLIT * B * NC * 4;

    prep_all<<<dim3(NK + 2 * UF_BLKS), 256, 0, stream>>>(conv_w, wtb, U_w, Ub, F_w, Fb);
    conv_mfma<<<dim3(B * S / CM), 512, 0, stream>>>(text, emb, wtb, conv_b, xf);
    attn_mfma<<<dim3(NC / 128, SSPLIT, B), 256, 0, stream>>>(xf, Ub, Fb, pl, pg);
    combine_kernel<<<dim3((B * NC + 255) / 256), 256, 0, stream>>>(pl, pg, f_b, out);
}